// Round 6
// baseline (340.321 us; speedup 1.0000x reference)
//
#include <hip/hip_runtime.h>
#include <math.h>

#define XS 512
#define YS 512
#define WDIM 256
#define NCELLS (XS * YS)          // 262144
#define K1_BLOCKS 2048
#define K1_THREADS 256            // 4 waves/block
#define NWAVES (K1_BLOCKS * (K1_THREADS / 64))  // 8192
#define CH 4                      // cells per wave per iteration (4 KB)
#define NITERS (NCELLS / (NWAVES * CH))         // 8
#define NSLOTS 32                 // atomic sink slots
#define SLOT_STRIDE 16            // u64s per slot stride = 128 B (one cacheline)

typedef float vfloat4 __attribute__((ext_vector_type(4)));

// Kernel 1: per-cell squared L2 distance, argmin.
// Ledger: serial+NT=347.8 | butterfly,noNT=363.0 | +32slot sink=362.6 |
// +NT+8deep pipeline=339.2. Reduction, sink, occupancy, per-stream depth all
// ~neutral; NT=-15us, depth=-9us. k1 still ~2TB/s vs 6.3 achievable.
// THIS round's single change: FRONTIER LOCALITY. Previously each of 8192
// waves privately streamed its own contiguous 32KB (8192 simultaneous DRAM
// page frontiers). The 6.6TB/s fill and m13's 6.3TB/s copy sweep ONE
// contiguous frontier (grid-stride). Now iteration `it` has the whole grid
// collectively read one contiguous 32MB window: cell(it,gw,c) =
// it*32768 + gw*4 + c. Body is otherwise the proven R3 butterfly + R5's
// NT loads + 1-deep prefetch; buf[2][4] keeps VGPRs lean for occupancy.
__global__ __launch_bounds__(K1_THREADS) void som_dist_kernel(
    const float* __restrict__ x,
    const float* __restrict__ W,
    unsigned long long* __restrict__ ws) {
  const int lane = threadIdx.x & 63;
  const int waveInBlock = threadIdx.x >> 6;
  const int gw = blockIdx.x * (K1_THREADS / 64) + waveInBlock;

  const vfloat4 xv = ((const vfloat4*)x)[lane];

  float bestD = 3.4e38f;
  int bestI = 0;

  const int r3 = lane & 3;   // cell-in-batch this lane owns after the butterfly
  const bool b0 = (lane & 1) != 0;
  const bool b1 = (lane & 2) != 0;

  vfloat4 buf[2][CH];  // ping-pong row data; indices static after full unroll

  {
    const vfloat4* p0 = (const vfloat4*)(W + (size_t)(gw * CH) * WDIM) + lane;
#pragma unroll
    for (int r = 0; r < CH; ++r)
      buf[0][r] = __builtin_nontemporal_load(p0 + r * (WDIM / 4));
  }

#pragma unroll
  for (int it = 0; it < NITERS; ++it) {
    // prefetch next iteration's 4 rows while reducing the current ones;
    // next window is 32MB away but the GRID frontier stays contiguous
    if (it < NITERS - 1) {
      const vfloat4* pn =
          (const vfloat4*)(W + ((size_t)(it + 1) * (NWAVES * CH) + (size_t)gw * CH) * WDIM) +
          lane;
#pragma unroll
      for (int r = 0; r < CH; ++r)
        buf[(it + 1) & 1][r] = __builtin_nontemporal_load(pn + r * (WDIM / 4));
    }

    const int cb = it * (NWAVES * CH) + gw * CH;

    float s0, s1, s2, s3;
    {
      const vfloat4 w0 = buf[it & 1][0];
      const vfloat4 w1 = buf[it & 1][1];
      const vfloat4 w2 = buf[it & 1][2];
      const vfloat4 w3 = buf[it & 1][3];
      float d;
      d = xv.x - w0.x; s0  = d * d;
      d = xv.y - w0.y; s0 += d * d;
      d = xv.z - w0.z; s0 += d * d;
      d = xv.w - w0.w; s0 += d * d;

      d = xv.x - w1.x; s1  = d * d;
      d = xv.y - w1.y; s1 += d * d;
      d = xv.z - w1.z; s1 += d * d;
      d = xv.w - w1.w; s1 += d * d;

      d = xv.x - w2.x; s2  = d * d;
      d = xv.y - w2.y; s2 += d * d;
      d = xv.z - w2.z; s2 += d * d;
      d = xv.w - w2.w; s2 += d * d;

      d = xv.x - w3.x; s3  = d * d;
      d = xv.y - w3.y; s3 += d * d;
      d = xv.z - w3.z; s3 += d * d;
      d = xv.w - w3.w; s3 += d * d;
    }

    // value-halving butterfly: 4 partials -> 1 value/lane, cell = cb+(lane&3)
    float keepA = b0 ? s1 : s0;
    float sendA = b0 ? s0 : s1;
    float t0 = keepA + __shfl_xor(sendA, 1, 64);   // cell (cb + b0)
    float keepB = b0 ? s3 : s2;
    float sendB = b0 ? s2 : s3;
    float t1 = keepB + __shfl_xor(sendB, 1, 64);   // cell (cb + 2 + b0)

    float keepC = b1 ? t1 : t0;
    float sendC = b1 ? t0 : t1;
    float v = keepC + __shfl_xor(sendC, 2, 64);    // cell (cb + (lane&3))

    v += __shfl_xor(v, 4, 64);
    v += __shfl_xor(v, 8, 64);
    v += __shfl_xor(v, 16, 64);
    v += __shfl_xor(v, 32, 64);

    // strict <: lane's cell index increases with it => lowest index on ties
    if (v < bestD) { bestD = v; bestI = cb + r3; }
  }

  // fp32 dist (>=0) bit pattern is order-monotone as u32; index in low 32.
  // Packed u64 min => lowest distance, ties broken by lowest index.
  unsigned long long packed =
      ((unsigned long long)__float_as_uint(bestD) << 32) | (unsigned int)bestI;

  // wave-level min across the 64 per-residue candidates
#pragma unroll
  for (int off = 32; off > 0; off >>= 1) {
    const unsigned long long o = __shfl_xor(packed, off, 64);
    packed = (o < packed) ? o : packed;
  }

  __shared__ unsigned long long sbest[K1_THREADS / 64];
  if (lane == 0) sbest[waveInBlock] = packed;
  __syncthreads();
  if (threadIdx.x == 0) {
    unsigned long long m = sbest[0];
#pragma unroll
    for (int i = 1; i < K1_THREADS / 64; ++i) {
      const unsigned long long v2 = sbest[i];
      m = (v2 < m) ? v2 : m;
    }
    // 32 cacheline-strided slots (measured neutral vs 1 slot, kept: harmless)
    atomicMin(ws + (blockIdx.x & (NSLOTS - 1)) * SLOT_STRIDE, m);
  }
}

// Kernel 2: reduce the 32 slots (L2-hot), write h; block 0 appends wx, wy.
__global__ __launch_bounds__(256) void som_h_kernel(
    const unsigned long long* __restrict__ ws,
    const int* __restrict__ time_step,
    float* __restrict__ out) {
  const int t = threadIdx.x;
  const int lane = t & 63;

  // lanes 0-31 and 32-63 each load all 32 slots; 5-step butterfly within each
  // 32-lane half leaves the global min in EVERY lane.
  unsigned long long v = ws[(lane & (NSLOTS - 1)) * SLOT_STRIDE];
#pragma unroll
  for (int off = 1; off < 32; off <<= 1) {
    const unsigned long long o = __shfl_xor(v, off, 64);
    v = (o < v) ? o : v;
  }

  const int flat = (int)(v & 0xFFFFFFFFULL);
  const int wx = flat >> 9;       // flat / 512
  const int wy = flat & (YS - 1); // flat % 512

  // decay = SIGMA * exp(-t / (1000/ln(SIGMA))), SIGMA = 2
  const float ts = (float)(*time_step);
  const float TIME_CONST = 1442.6950408889634f;  // 1000 / ln(2)
  const float decay = 2.0f * expf(-ts / TIME_CONST);
  const float denom = 2.0f * decay * decay;
  const float inv = -1.0f / denom;

  // h[i][j] = exp(-((i-wx)^2 + (j-wy)^2) / denom); one float4 per thread
  const int e = blockIdx.x * 1024 + t * 4;
  const int i = e >> 9;
  const int j0 = e & (YS - 1);
  const float di = (float)(i - wx);
  const float di2 = di * di;

  const float d0 = (float)(j0 + 0 - wy);
  const float d1 = (float)(j0 + 1 - wy);
  const float d2 = (float)(j0 + 2 - wy);
  const float d3 = (float)(j0 + 3 - wy);
  vfloat4 r;
  r.x = expf((di2 + d0 * d0) * inv);
  r.y = expf((di2 + d1 * d1) * inv);
  r.z = expf((di2 + d2 * d2) * inv);
  r.w = expf((di2 + d3 * d3) * inv);
  ((vfloat4*)out)[e >> 2] = r;

  if (blockIdx.x == 0 && t == 0) {
    out[NCELLS] = (float)wx;      // output order: h, wx, wy
    out[NCELLS + 1] = (float)wy;
  }
}

extern "C" void kernel_launch(void* const* d_in, const int* in_sizes, int n_in,
                              void* d_out, int out_size, void* d_ws, size_t ws_size,
                              hipStream_t stream) {
  const float* x = (const float*)d_in[0];
  const float* W = (const float*)d_in[1];
  const int* ts = (const int*)d_in[2];
  float* out = (float*)d_out;
  unsigned long long* ws = (unsigned long long*)d_ws;

  // Init all 32 strided slots to u64-max so atomicMin never sees poison.
  (void)hipMemsetAsync(ws, 0xFF, NSLOTS * SLOT_STRIDE * 8, stream);
  som_dist_kernel<<<K1_BLOCKS, K1_THREADS, 0, stream>>>(x, W, ws);
  som_h_kernel<<<NCELLS / 1024, 256, 0, stream>>>(ws, ts, out);
}